// Round 8
// baseline (255.506 us; speedup 1.0000x reference)
//
#include <hip/hip_runtime.h>

typedef short bf16x8 __attribute__((ext_vector_type(8)));
typedef float f32x4 __attribute__((ext_vector_type(4)));
typedef unsigned short u16;

__device__ __forceinline__ u16 f2bf(float f) {
    unsigned u = __builtin_bit_cast(unsigned, f);
    return (u16)((u + 0x7fffu + ((u >> 16) & 1u)) >> 16);   // RNE
}

// ---------------- kernel 1 (fused prep): ------------------------------------
// blocks [0,1024):      xpad[b][r][d] bf16 (r<4096 zeros, 4096+t = x[b,t,:])
// blocks [1024,1064):   ApT/AmT[k][o][d] = (Mp +/- Mm)[k][d][o]
// blocks [1064,1192):   zero d_out (2 MiB); block 1064 also zeros the counter
__global__ void k_prep(const float* __restrict__ x, u16* __restrict__ xpad,
                       const float* __restrict__ Mp, const float* __restrict__ Mm,
                       float* __restrict__ ApT, float* __restrict__ AmT,
                       float* __restrict__ out, int* __restrict__ counter) {
    __shared__ float tp[64 * 65], tm[64 * 65];
    if (blockIdx.x < 1024) {
        int gid = blockIdx.x * 256 + threadIdx.x;
        int b   = gid >> 17;
        int rem = gid & 131071;
        int r   = rem >> 4;
        int c4  = rem & 15;
        u16 o0 = 0, o1 = 0, o2 = 0, o3 = 0;
        if (r >= 4096) {
            const f32x4 v = *(const f32x4*)(x + ((b << 12) + (r - 4096)) * 64 + c4 * 4);
            o0 = f2bf(v.x); o1 = f2bf(v.y); o2 = f2bf(v.z); o3 = f2bf(v.w);
        }
        u16* p = xpad + ((b << 13) + r) * 64 + c4 * 4;
        p[0] = o0; p[1] = o1; p[2] = o2; p[3] = o3;
    } else if (blockIdx.x < 1064) {
        const int k = blockIdx.x - 1024, tid = threadIdx.x;
        for (int f = tid; f < 4096; f += 256) {          // f = d*64 + o
            int d = f >> 6, o = f & 63;
            float p = Mp[k * 4096 + f], m = Mm[k * 4096 + f];
            tp[o * 65 + d] = p + m;
            tm[o * 65 + d] = p - m;
        }
        __syncthreads();
        for (int f = tid; f < 4096; f += 256) {          // f = o*64 + d
            int o = f >> 6, d = f & 63;
            ApT[k * 4096 + f] = tp[o * 65 + d];
            AmT[k * 4096 + f] = tm[o * 65 + d];
        }
    } else {
        const int bz = blockIdx.x - 1064;                // 128 blocks x 4096 floats
        if (bz == 0 && threadIdx.x == 0) *counter = 0;
        float* po = out + bz * 4096;
        #pragma unroll
        for (int i = 0; i < 4; ++i)
            *(f32x4*)(po + (threadIdx.x + i * 256) * 4) = (f32x4){0.f, 0.f, 0.f, 0.f};
    }
}

// ---------------- kernel 2: build Wtot[s][o][d] (bf16) -----------------------
// W[s][o][d] = sum_k phi[s,k]*(Mp + sgn(s)*Mm)[k,d,o]  (+ M[o,d,s] for s<3)
__global__ __launch_bounds__(256)
void k_build_w(const float* __restrict__ phi, const float* __restrict__ ApT,
               const float* __restrict__ AmT, const float* __restrict__ Mar,
               u16* __restrict__ wg) {
    const int sb = blockIdx.x;                 // 0..63  -> 64 s-values
    const int qb = blockIdx.y;                 // 0..15  -> 256 q = o*64+d
    const int s0 = sb * 64;
    const int q  = qb * 256 + threadIdx.x;
    const int o  = q >> 6, d = q & 63;

    float ap[40], am[40];
    #pragma unroll
    for (int k = 0; k < 40; ++k) { ap[k] = ApT[k * 4096 + q]; am[k] = AmT[k * 4096 + q]; }

    for (int j = 0; j < 64; j += 2) {
        const float* ph = phi + (s0 + j) * 40;           // wave-uniform -> s_load
        float a0 = 0.f, a1 = 0.f, b0 = 0.f, b1 = 0.f;
        #pragma unroll
        for (int k = 0; k < 40; k += 2) { a0 += ph[k] * ap[k]; a1 += ph[k + 1] * ap[k + 1]; }
        #pragma unroll
        for (int k = 0; k < 40; k += 2) { b0 += ph[40 + k] * am[k]; b1 += ph[41 + k] * am[k + 1]; }
        float ev = a0 + a1, ov = b0 + b1;
        int s = s0 + j;
        if (s < 3)     ev += Mar[o * 192 + d * 3 + s];
        if (s + 1 < 3) ov += Mar[o * 192 + d * 3 + s + 1];
        wg[(size_t)s * 4096 + q]       = f2bf(ev);
        wg[(size_t)(s + 1) * 4096 + q] = f2bf(ov);
    }
}

// ---------------- kernel 3: triangular conv-GEMM, slide-reuse K-loop ---------
// Waves = (khalf, batch): each wave contracts d in [khalf*32, +32), mt=8 x nt=4.
// Inner loop over s-groups {dl, dl+16, dl+32, dl+48}: A-frag slide symmetry
// frag(mt,s)==frag(mt+1,s+16) -> 11 A-reads per 4 s (vs 32). W group (4 tiles,
// 32 KB) single-buffered in LDS, VGPR-prefetched one group ahead.
// LDS: 0.27 ops/MFMA vs R7's 0.44 -> ceiling ~57-90% (was ~41%).

template<int SLEN>
__device__ __forceinline__ void run_tiles(const u16* __restrict__ wg,
                                          const u16* xb, u16* wsm,
                                          int s0, int kq, int m15,
                                          int l0, int l1, int f0, int f1,
                                          f32x4 (&acc)[8][4]) {
    constexpr int G = SLEN / 16;
    // initial prefetch (group dl=0)
    bf16x8 pre[G][2];
    #pragma unroll
    for (int t = 0; t < G; ++t) {
        const u16* wp = wg + (size_t)(s0 + 16 * t) * 4096;
        pre[t][0] = *(const bf16x8*)(wp + f0 * 8);
        pre[t][1] = *(const bf16x8*)(wp + f1 * 8);
    }
    #pragma unroll 1
    for (int dl = 0; dl < 16; ++dl) {
        __syncthreads();                                 // prior group reads done
        #pragma unroll
        for (int t = 0; t < G; ++t) {
            *(bf16x8*)(wsm + t * 4096 + l0) = pre[t][0];
            *(bf16x8*)(wsm + t * 4096 + l1) = pre[t][1];
        }
        // A-frags for g=0 (sigma = 0..7), xs stable -> overlap with barrier
        bf16x8 af[8 + G - 1];
        const int rbase = m15 + (SLEN - 1) - dl;
        #pragma unroll
        for (int sg = 0; sg < 8; ++sg) {
            int r = rbase + 16 * sg;
            af[(G - 1) + sg] = *(const bf16x8*)(xb + (r * 8 + (kq ^ (r & 7))) * 8);
        }
        __syncthreads();                                 // W group visible
        if (dl < 15) {                                   // prefetch next group
            #pragma unroll
            for (int t = 0; t < G; ++t) {
                const u16* wp = wg + (size_t)(s0 + dl + 1 + 16 * t) * 4096;
                pre[t][0] = *(const bf16x8*)(wp + f0 * 8);
                pre[t][1] = *(const bf16x8*)(wp + f1 * 8);
            }
        }
        #pragma unroll
        for (int g = 0; g < G; ++g) {
            if (g > 0) {                                 // one new A-frag (sigma=-g)
                int r = rbase - 16 * g;
                af[(G - 1) - g] = *(const bf16x8*)(xb + (r * 8 + (kq ^ (r & 7))) * 8);
            }
            bf16x8 bf[4];
            #pragma unroll
            for (int nt = 0; nt < 4; ++nt) {
                int o = nt * 16 + m15;
                bf[nt] = *(const bf16x8*)(wsm + g * 4096 + (o * 8 + (kq ^ (o & 7))) * 8);
            }
            #pragma unroll
            for (int mt = 0; mt < 8; ++mt)
                #pragma unroll
                for (int nt = 0; nt < 4; ++nt)
                    acc[mt][nt] = __builtin_amdgcn_mfma_f32_16x16x32_bf16(
                        af[(G - 1) + mt - g], bf[nt], acc[mt][nt], 0, 0, 0);
        }
    }
}

__global__ __launch_bounds__(256, 2)
void k_spectral(const u16* __restrict__ xpad, const u16* __restrict__ wg,
                float* __restrict__ out, int* __restrict__ counter) {
    __shared__ __align__(16) u16 xs[2 * 191 * 64];       // 47.75 KB x window
    __shared__ __align__(16) u16 wsm[4 * 64 * 64];       // 32 KB: 4 W tiles / merge buf
    __shared__ int sh;

    const int tid  = threadIdx.x;
    const int lane = tid & 63, w = tid >> 6;
    const int m15  = lane & 15, q4 = lane >> 4;
    const int khalf = w >> 1, batch = w & 1;             // wave = (k-half, batch)
    const int kq = khalf * 4 + q4;
    const int f0 = tid * 2, f1 = tid * 2 + 1;            // W staging granules
    const int l0 = (((f0 >> 3) * 8) + ((f0 & 7) ^ ((f0 >> 3) & 7))) * 8;
    const int l1 = (((f1 >> 3) * 8) + ((f1 & 7) ^ ((f1 >> 3) & 7))) * 8;

    for (;;) {
        __syncthreads();                                 // xs/wsm/sh reuse guard
        if (tid == 0) sh = atomicAdd(counter, 1);
        __syncthreads();
        const int U = sh;
        if (U >= 1120) break;

        // taper: U<992 -> full unit; else half task (32-s) of unit 992+(U-992)/2
        int mu = U, shalf = 0, slen = 64;
        if (U >= 992) { mu = 992 + ((U - 992) >> 1); shalf = (U - 992) & 1; slen = 32; }
        // J-major unit decode: group g=J>>1, G(g)=g(65-g), column cnt=32-g
        int g = 0;
        #pragma unroll 1
        while (g < 31 && (g + 1) * (64 - g) <= mu) ++g;
        const int rem = mu - g * (65 - g);
        const int cnt = 32 - g;
        const int col = (rem >= cnt) ? 1 : 0;
        const int J = 2 * g + col;
        const int I = g + (col ? rem - cnt : rem);
        const int t0 = I << 7, s0 = (J << 6) + (shalf << 5);
        const int nrows = 127 + slen;
        const int base = 4096 + t0 - s0 - (slen - 1);    // window start row in xpad

        // ---- stage x window: nrows rows/batch ----
        #pragma unroll
        for (int b = 0; b < 2; ++b) {
            #pragma unroll 1
            for (int f = tid; f < nrows * 8; f += 256) {
                int r = f >> 3, c = f & 7;
                bf16x8 v = *(const bf16x8*)(xpad + (size_t)((b << 13) + base + r) * 64 + c * 8);
                *(bf16x8*)(xs + ((b * 191 + r) * 8 + (c ^ (r & 7))) * 8) = v;
            }
        }

        f32x4 acc[8][4];
        #pragma unroll
        for (int mt = 0; mt < 8; ++mt)
            #pragma unroll
            for (int nt = 0; nt < 4; ++nt)
                acc[mt][nt] = (f32x4){0.f, 0.f, 0.f, 0.f};

        const u16* xb = xs + batch * (191 * 64);

        if (slen == 64)
            run_tiles<64>(wg, xb, wsm, s0, kq, m15, l0, l1, f0, f1, acc);
        else
            run_tiles<32>(wg, xb, wsm, s0, kq, m15, l0, l1, f0, f1, acc);

        // ---- merge khalf-1 partials into khalf-0 accs via LDS (wsm dead) ----
        float* fs = (float*)wsm;                         // 4096 floats (16 KB)
        #pragma unroll
        for (int rd = 0; rd < 4; ++rd) {
            __syncthreads();
            if (khalf == 1) {
                #pragma unroll
                for (int i = 0; i < 8; ++i) {
                    int ti = rd * 8 + i;
                    *(f32x4*)(fs + (batch * 8 + i) * 256 + lane * 4) = acc[ti >> 2][ti & 3];
                }
            }
            __syncthreads();
            if (khalf == 0) {
                #pragma unroll
                for (int i = 0; i < 8; ++i) {
                    int ti = rd * 8 + i;
                    f32x4 v = *(const f32x4*)(fs + (batch * 8 + i) * 256 + lane * 4);
                    acc[ti >> 2][ti & 3] += v;
                }
            }
        }

        // ---- epilogue (khalf-0 waves only): coalesced fp32 atomics ----
        if (khalf == 0) {
            #pragma unroll
            for (int mt = 0; mt < 8; ++mt) {
                int t = t0 + mt * 16 + q4 * 4;
                #pragma unroll
                for (int nt = 0; nt < 4; ++nt) {
                    int o = nt * 16 + m15;
                    float* op = out + (size_t)((batch << 12) + t) * 64 + o;
                    #pragma unroll
                    for (int r = 0; r < 4; ++r)
                        atomicAdd(op + r * 64, acc[mt][nt][r]);
                }
            }
        }
    }
}

// ---------------------------------------------------------------------------
extern "C" void kernel_launch(void* const* d_in, const int* in_sizes, int n_in,
                              void* d_out, int out_size, void* d_ws, size_t ws_size,
                              hipStream_t stream) {
    const float* x   = (const float*)d_in[0];   // (2, 4096, 64)
    const float* phi = (const float*)d_in[1];   // (4096, 40)
    const float* M   = (const float*)d_in[2];   // (64, 64, 3)
    const float* Mp  = (const float*)d_in[3];   // (40, 64, 64)
    const float* Mm  = (const float*)d_in[4];   // (40, 64, 64)
    float* out = (float*)d_out;                 // (2, 4096, 64)

    // ws: [0,4) counter | 4096: xpad 2 MiB | wg 32 MiB | ApT/AmT 2x640 KiB
    int* counter = (int*)d_ws;
    u16* xpad = (u16*)((char*)d_ws + 4096);
    u16* wg   = (u16*)((char*)d_ws + 4096 + 2097152);
    float* ApT = (float*)((char*)d_ws + 4096 + 2097152 + 33554432);
    float* AmT = ApT + 40 * 4096;

    k_prep<<<1192, 256, 0, stream>>>(x, xpad, Mp, Mm, ApT, AmT, out, counter);
    k_build_w<<<dim3(64, 16), 256, 0, stream>>>(phi, ApT, AmT, M, wg);
    k_spectral<<<512, 256, 0, stream>>>(xpad, wg, out, counter);
}